// Round 2
// baseline (1179.556 us; speedup 1.0000x reference)
//
#include <hip/hip_runtime.h>
#include <cmath>

#define T_STEPS 4096
#define BATCH   128
#define NIN     96
#define NH      64

typedef unsigned short u16;

__device__ __forceinline__ float bf2f(u16 u) {
    unsigned v = ((unsigned)u) << 16;
    return __builtin_bit_cast(float, v);
}
// f64 decay constants, mirroring np.exp(-DT/TAU) f64 scalars (NEP-50 strong promotion)
__device__ __forceinline__ double d_alpha() { return exp(-0.004 / (log1p(exp(1.0)) * 0.01)); }
__device__ __forceinline__ double d_beta()  { return exp(-0.004 / (log1p(exp(1.0)) * 0.02)); }

// Count "impossible-as-bf16" u16 patterns (f32 mantissa halves decode as huge/inf/nan).
__device__ __forceinline__ int sniff_part(const void* p, int nscan, int tid, int nthr) {
    const u16* q = (const u16*)p;
    int cnt = 0;
    for (int i = tid; i < nscan; i += nthr) {
        float v = bf2f(q[i]);
        if (!(fabsf(v) < 1e4f)) cnt++;
    }
    return cnt;
}
__device__ __forceinline__ int wave_sum(int c) {
#pragma unroll
    for (int d = 32; d >= 1; d >>= 1) c += __shfl_xor(c, d, 64);
    return c;
}

// 16 k-ascending FMAs into each of the 64 per-lane accumulators.
// W read wave-uniform from LDS (broadcast ds_read_b128, conflict-free).
// Chain order per output h: single accumulator, k ascending, fmaf — bit-exact
// match of the BLAS sgemm microkernel rounding (MUST NOT change).
__device__ __forceinline__ void acc_chunk(float* __restrict__ acc,
                                          const float* __restrict__ xr,
                                          const float* __restrict__ wbase) {
#pragma unroll
    for (int h = 0; h < 64; ++h) {
        const float4* wr = (const float4*)(wbase + h * NIN);
        const float4 w0 = wr[0], w1 = wr[1], w2 = wr[2], w3 = wr[3];
        float c = acc[h];
        c = fmaf(xr[0],  w0.x, c); c = fmaf(xr[1],  w0.y, c);
        c = fmaf(xr[2],  w0.z, c); c = fmaf(xr[3],  w0.w, c);
        c = fmaf(xr[4],  w1.x, c); c = fmaf(xr[5],  w1.y, c);
        c = fmaf(xr[6],  w1.z, c); c = fmaf(xr[7],  w1.w, c);
        c = fmaf(xr[8],  w2.x, c); c = fmaf(xr[9],  w2.y, c);
        c = fmaf(xr[10], w2.z, c); c = fmaf(xr[11], w2.w, c);
        c = fmaf(xr[12], w3.x, c); c = fmaf(xr[13], w3.y, c);
        c = fmaf(xr[14], w3.z, c); c = fmaf(xr[15], w3.w, c);
        acc[h] = c;
    }
}

// ---------------- Phase 1: cur[(t*B+b), h] = seq-fma dot(x[(t-1)*B+b,:], Wh[h,:]) in f32.
// One LANE per row, acc[64] in VGPRs; W broadcast from LDS; x via uint4 loads.
__global__ __launch_bounds__(256) void k_cur(const void* __restrict__ xv,
                                             const void* __restrict__ whv,
                                             float* __restrict__ cur) {
    const int NROWC = (T_STEPS - 1) * BATCH;  // 524160
    const int tid = threadIdx.x;
    __shared__ int s_cnt[2];
    __shared__ __align__(16) float whs[NH * NIN];  // [h][96] f32, rows 384B (16B-aligned)
    if (tid < 2) s_cnt[tid] = 0;
    __syncthreads();
    int c0 = sniff_part(xv, 512, tid, 256);
    int c1 = sniff_part(whv, 512, tid, 256);
    if (c0) atomicAdd(&s_cnt[0], c0);
    if (c1) atomicAdd(&s_cnt[1], c1);
    __syncthreads();
    const bool fx = s_cnt[0] >= 32, fw = s_cnt[1] >= 32;

    if (fw) {
        const float* w = (const float*)whv;
        for (int s = tid; s < NH * NIN; s += 256) whs[s] = w[s];
    } else {
        const u16* w = (const u16*)whv;
        for (int s = tid; s < NH * NIN; s += 256) whs[s] = bf2f(w[s]);
    }
    __syncthreads();

    const long r = (long)blockIdx.x * 256 + tid;  // one row per lane
    if (r >= NROWC) {
        // exactly 128 leftover threads in the last block: zero cur rows [0,128) (t=0)
        const long z = r - NROWC;
        if (z < BATCH) {
            float4 zero = {0.f, 0.f, 0.f, 0.f};
            float4* zp = (float4*)(cur + z * NH);
#pragma unroll
            for (int j = 0; j < 16; ++j) zp[j] = zero;
        }
        return;
    }

    float acc[64];
#pragma unroll
    for (int h = 0; h < 64; ++h) acc[h] = 0.f;

    if (!fx) {
        const uint4* xq = (const uint4*)((const u16*)xv + (size_t)r * NIN);  // 12 uint4/row
        uint4 n0 = xq[0], n1 = xq[1];  // prefetch chunk 0
#pragma unroll 1
        for (int kb = 0; kb < 6; ++kb) {
            const uint4 a = n0, b = n1;
            if (kb < 5) { n0 = xq[(kb + 1) * 2]; n1 = xq[(kb + 1) * 2 + 1]; }
            const unsigned ua[8] = {a.x, a.y, a.z, a.w, b.x, b.y, b.z, b.w};
            float xr[16];
#pragma unroll
            for (int j = 0; j < 8; ++j) {
                xr[2 * j]     = bf2f((u16)(ua[j] & 0xFFFFu));
                xr[2 * j + 1] = bf2f((u16)(ua[j] >> 16));
            }
            acc_chunk(acc, xr, whs + kb * 16);
        }
    } else {
        const float4* xq = (const float4*)((const float*)xv + (size_t)r * NIN);  // 24 float4/row
        float4 n0 = xq[0], n1 = xq[1], n2 = xq[2], n3 = xq[3];
#pragma unroll 1
        for (int kb = 0; kb < 6; ++kb) {
            const float4 a0 = n0, a1 = n1, a2 = n2, a3 = n3;
            if (kb < 5) {
                n0 = xq[(kb + 1) * 4];     n1 = xq[(kb + 1) * 4 + 1];
                n2 = xq[(kb + 1) * 4 + 2]; n3 = xq[(kb + 1) * 4 + 3];
            }
            const float xr[16] = {a0.x, a0.y, a0.z, a0.w, a1.x, a1.y, a1.z, a1.w,
                                  a2.x, a2.y, a2.z, a2.w, a3.x, a3.y, a3.z, a3.w};
            acc_chunk(acc, xr, whs + kb * 16);
        }
    }

    float4* op = (float4*)(cur + ((size_t)r + BATCH) * NH);
#pragma unroll
    for (int j = 0; j < 16; ++j) {
        float4 v;
        v.x = acc[4 * j]; v.y = acc[4 * j + 1]; v.z = acc[4 * j + 2]; v.w = acc[4 * j + 3];
        op[j] = v;
    }
}

// ---------------- Phase 2: sequential scan, f64 hidden states.
// 1 block = 1 batch element, 1 wave, lane = hidden neuron.
// rec gather: up to 8 set-bit indices extracted scalar-side, all 8 ds_read_b32
// issued before any wait (pipelined latency), f64 tree-sum (exact: f64 sums of
// f32 values, mantissa span << 53 bits -> identical to k-ascending sum).
// Spike decision hoisted off the f64 chain tail: s <=> ombeta*rec + pre > rhs,
// with pre/rhs computed during the LDS wait. Carried syn/mem expressions are
// UNCHANGED (bit-identical state trajectory when no decision flips; f64
// decision perturbation ~2^-50 relative -> flip probability ~0).
__global__ __launch_bounds__(64, 1) void k_scan(const float* __restrict__ cur,
                                                const void* __restrict__ vv,
                                                _Float16* __restrict__ ftr) {
    const int b = blockIdx.x, h = threadIdx.x;
    const double alpha = d_alpha(), beta = d_beta(), ombeta = 1.0 - beta;
    const float alphaf = (float)alpha, betaf = (float)beta, ombetaf = (float)ombeta;

    const bool fv = wave_sum(sniff_part(vv, 512, h, 64)) >= 32;

    __shared__ float vlds[65 * NH];  // vlds[k*64+h] = V[h][k]; row 64 = zeros (pad target)
    if (fv) {
        const float* vp = (const float*)vv;
        for (int s = h; s < NH * NH; s += 64) vlds[((s & 63) << 6) | (s >> 6)] = vp[s];
    } else {
        const u16* vp = (const u16*)vv;
        for (int s = h; s < NH * NH; s += 64) vlds[((s & 63) << 6) | (s >> 6)] = bf2f(vp[s]);
    }
    vlds[(64 << 6) | h] = 0.0f;  // zero pad row for unused gather slots
    __syncthreads();

    double syn = 0.0, mem = 0.0;
    float e = 0.f, f = 0.f, spkf = 0.f;
    unsigned long long mask = 0ull;

    const size_t STEP = (size_t)BATCH * NH;
    const float* cp = cur + (size_t)b * NH + h;
    _Float16* fp = ftr + (size_t)b * NH + h;

    float cbuf[8];  // 8-deep prefetch pipeline hides HBM latency on cur reads
#pragma unroll
    for (int j = 0; j < 8; ++j) cbuf[j] = cp[(size_t)j * STEP];

    for (int tt = 0; tt < T_STEPS; tt += 8) {
#pragma unroll
        for (int j = 0; j < 8; ++j) {
            const float c = cbuf[j];
            int tn = tt + j + 8;
            if (tn > T_STEPS - 1) tn = T_STEPS - 1;  // clamped tail loads, values unused
            cbuf[j] = cp[(size_t)tn * STEP];

            // decision-side precompute: overlaps the LDS gather latency.
            const double pre = ombeta * fma(alpha, syn, (double)c);  // ombeta*(a*syn + c)
            const double rhs = 1.0 - beta * mem;

            double rec = 0.0;
            unsigned long long m = mask;
            if (m) {
                // extract up to 8 set bits (scalar chain); pad with zero row 64
                const int k0 = (int)__builtin_ctzll(m); m &= m - 1;
                const int k1 = m ? (int)__builtin_ctzll(m) : 64; m &= m - 1;
                const int k2 = m ? (int)__builtin_ctzll(m) : 64; m &= m - 1;
                const int k3 = m ? (int)__builtin_ctzll(m) : 64; m &= m - 1;
                const int k4 = m ? (int)__builtin_ctzll(m) : 64; m &= m - 1;
                const int k5 = m ? (int)__builtin_ctzll(m) : 64; m &= m - 1;
                const int k6 = m ? (int)__builtin_ctzll(m) : 64; m &= m - 1;
                const int k7 = m ? (int)__builtin_ctzll(m) : 64; m &= m - 1;
                // 8 independent reads, one wait
                const float r0 = vlds[(k0 << 6) | h];
                const float r1 = vlds[(k1 << 6) | h];
                const float r2 = vlds[(k2 << 6) | h];
                const float r3 = vlds[(k3 << 6) | h];
                const float r4 = vlds[(k4 << 6) | h];
                const float r5 = vlds[(k5 << 6) | h];
                const float r6 = vlds[(k6 << 6) | h];
                const float r7 = vlds[(k7 << 6) | h];
                rec = (((double)r0 + (double)r1) + ((double)r2 + (double)r3))
                    + (((double)r4 + (double)r5) + ((double)r6 + (double)r7));
                while (m) {  // rare: >8 spikes in one step
                    const int k = (int)__builtin_ctzll(m);
                    m &= m - 1;
                    rec += (double)vlds[(k << 6) | h];
                }
            }

            // spike decision: algebraically == (beta*mem + ombeta*syn' > 1)
            const bool s = fma(ombeta, rec, pre) > rhs;

            // carried states: SAME source expressions as the passing kernel
            syn = alpha * syn + ((double)c + rec);
            mem = beta * mem + ombeta * syn;

            // readout traces driven by PREVIOUS spikes (before this step's mask update)
            e = fmaf(alphaf, e, spkf);
            f = fmaf(betaf, f, ombetaf * e);
            fp[(size_t)(tt + j) * STEP] = (_Float16)f;

            mem = s ? 0.0 : mem;
            spkf = s ? 1.0f : 0.0f;
            mask = __ballot(s);
        }
    }
}

// ---------------- Phase 3: preds[t,b,o] = sum_h Wo[o,h]*f[t,b,h] -> f32 output [T,B,2].
// Stage 256 rows (32 KB f16) through LDS with coalesced dword loads; padded
// stride 34 dwords (bank stride 2 -> 2-way aliasing, free) for both write+read.
__global__ __launch_bounds__(256) void k_out(const _Float16* __restrict__ ftr,
                                             const void* __restrict__ wov,
                                             float* __restrict__ out) {
    const int tid = threadIdx.x;
    __shared__ unsigned tile[256 * 34];  // row r at tile[r*34 .. r*34+32)
    __shared__ float wo[2][64];
    const bool fo = sniff_part(wov, 120, 0, 1) >= 7;
    if (fo) {
        if (tid < 128) wo[tid >> 6][tid & 63] = ((const float*)wov)[tid];
    } else {
        if (tid < 128) wo[tid >> 6][tid & 63] = bf2f(((const u16*)wov)[tid]);
    }

    // coalesced stage: 256 rows * 32 dwords = 8192 dwords, 256 threads * 32 iters
    const unsigned* src = (const unsigned*)(ftr + (size_t)blockIdx.x * 256 * NH);
#pragma unroll
    for (int i = 0; i < 32; ++i) {
        const int s = i * 256 + tid;
        tile[(s >> 5) * 34 + (s & 31)] = src[s];
    }
    __syncthreads();

    const size_t idx = (size_t)blockIdx.x * 256 + tid;  // row = t*B + b
    const unsigned* up = &tile[tid * 34];
    float d0 = 0.f, d1 = 0.f;
#pragma unroll
    for (int j = 0; j < 32; ++j) {
        const unsigned u = up[j];
        const float f0 = (float)__builtin_bit_cast(_Float16, (unsigned short)(u & 0xFFFFu));
        const float f1 = (float)__builtin_bit_cast(_Float16, (unsigned short)(u >> 16));
        d0 = fmaf(f0, wo[0][2 * j], d0);
        d1 = fmaf(f0, wo[1][2 * j], d1);
        d0 = fmaf(f1, wo[0][2 * j + 1], d0);
        d1 = fmaf(f1, wo[1][2 * j + 1], d1);
    }
    float2 r; r.x = d0; r.y = d1;
    ((float2*)out)[idx] = r;  // f32 [T,B,2] row-major
}

// ---------------- Fallback: fully fused, zero workspace, f64 states, f32 output.
__global__ __launch_bounds__(64) void k_fused(const void* __restrict__ xv,
                                              const void* __restrict__ whv,
                                              const void* __restrict__ vv,
                                              const void* __restrict__ wov,
                                              float* __restrict__ out) {
    const int b = blockIdx.x, h = threadIdx.x;
    const double alpha = d_alpha(), beta = d_beta(), ombeta = 1.0 - beta;

    const bool fx = wave_sum(sniff_part(xv, 512, h, 64)) >= 32;
    const bool fw = wave_sum(sniff_part(whv, 512, h, 64)) >= 32;
    const bool fv = wave_sum(sniff_part(vv, 512, h, 64)) >= 32;
    const bool fo = wave_sum(sniff_part(wov, 120, h, 64)) >= 7;

    __shared__ float vlds[NH * NH];  // vlds[k*64+h] = V[h][k]
    __shared__ float whl[NIN * NH];  // whl[i*64+h] = Wh[h][i]
    if (fv) { const float* vp = (const float*)vv;
        for (int s = h; s < NH * NH; s += 64) vlds[((s & 63) << 6) | (s >> 6)] = vp[s]; }
    else    { const u16* vp = (const u16*)vv;
        for (int s = h; s < NH * NH; s += 64) vlds[((s & 63) << 6) | (s >> 6)] = bf2f(vp[s]); }
    if (fw) { const float* wp = (const float*)whv;
        for (int s = h; s < NH * NIN; s += 64) whl[(s % 96) * 64 + (s / 96)] = wp[s]; }
    else    { const u16* wp = (const u16*)whv;
        for (int s = h; s < NH * NIN; s += 64) whl[(s % 96) * 64 + (s / 96)] = bf2f(wp[s]); }
    __syncthreads();

    double wo0, wo1;
    if (fo) { wo0 = (double)((const float*)wov)[h]; wo1 = (double)((const float*)wov)[64 + h]; }
    else    { wo0 = (double)bf2f(((const u16*)wov)[h]); wo1 = (double)bf2f(((const u16*)wov)[64 + h]); }

    double syn = 0.0, mem = 0.0, syno0 = 0.0, memo0 = 0.0, syno1 = 0.0, memo1 = 0.0;
    double spkd = 0.0;
    unsigned long long mask = 0ull;

    for (int t = 0; t < T_STEPS; ++t) {
        float c = 0.0f;
        if (t > 0) {
            const size_t off = ((size_t)(t - 1) * BATCH + b) * NIN;
            if (fx) { const float* xp = (const float*)xv + off;
                for (int i = 0; i < NIN; ++i) c = fmaf(xp[i], whl[i * 64 + h], c); }
            else    { const u16* xp = (const u16*)xv + off;
                for (int i = 0; i < NIN; ++i) c = fmaf(bf2f(xp[i]), whl[i * 64 + h], c); }
        }
        double rec = 0.0;
        unsigned long long m = mask;
        while (m) { const int k = __builtin_ctzll(m); m &= m - 1; rec += (double)vlds[(k << 6) | h]; }

        syn = alpha * syn + ((double)c + rec);
        mem = beta * mem + ombeta * syn;

        double p0 = spkd * wo0, p1 = spkd * wo1;
#pragma unroll
        for (int d = 32; d >= 1; d >>= 1) { p0 += __shfl_xor(p0, d, 64); p1 += __shfl_xor(p1, d, 64); }
        syno0 = alpha * syno0 + p0;
        memo0 = beta * memo0 + ombeta * syno0;
        syno1 = alpha * syno1 + p1;
        memo1 = beta * memo1 + ombeta * syno1;
        if (h == 0) {
            const size_t w = ((size_t)t * BATCH + b) * 2;
            out[w] = (float)memo0;
            out[w + 1] = (float)memo1;
        }

        const bool s = mem > 1.0;
        mem = s ? 0.0 : mem;
        spkd = s ? 1.0 : 0.0;
        mask = __ballot(s);
    }
}

extern "C" void kernel_launch(void* const* d_in, const int* in_sizes, int n_in,
                              void* d_out, int out_size, void* d_ws, size_t ws_size,
                              hipStream_t stream) {
    (void)in_sizes; (void)out_size;
    if (n_in < 4) return;
    const void* x  = d_in[0];   // [T,B,IN]  f32 or bf16 (sniff-verified)
    const void* Wh = d_in[1];   // [H,IN]
    const void* V  = d_in[2];   // [H,H]
    const void* Wo = d_in[3];   // [OUT,H]
    float* out = (float*)d_out; // [T,B,2] float32

    const size_t NROW = (size_t)T_STEPS * BATCH;       // 524288
    const size_t curB = NROW * NH * sizeof(float);     // 134 MB
    const size_t ftrB = NROW * NH * sizeof(_Float16);  // 67 MB

    if (ws_size >= curB + ftrB) {
        float* cur = (float*)d_ws;
        _Float16* ftr = (_Float16*)((char*)d_ws + curB);
        // 2048 blocks * 256 threads = 524288 = 524160 compute rows + 128 zero-fill rows
        const int NBLK = (int)(NROW / 256);
        k_cur<<<NBLK, 256, 0, stream>>>(x, Wh, cur);
        k_scan<<<BATCH, 64, 0, stream>>>(cur, V, ftr);
        k_out<<<NROW / 256, 256, 0, stream>>>(ftr, Wo, out);
    } else {
        k_fused<<<BATCH, 64, 0, stream>>>(x, Wh, V, Wo, out);
    }
}

// Round 3
// 940.583 us; speedup vs baseline: 1.2541x; 1.2541x over previous
//
#include <hip/hip_runtime.h>
#include <cmath>

#define T_STEPS 4096
#define BATCH   128
#define NIN     96
#define NH      64

typedef unsigned short u16;

__device__ __forceinline__ float bf2f(u16 u) {
    unsigned v = ((unsigned)u) << 16;
    return __builtin_bit_cast(float, v);
}
// f64 decay constants, mirroring np.exp(-DT/TAU) f64 scalars (NEP-50 strong promotion)
__device__ __forceinline__ double d_alpha() { return exp(-0.004 / (log1p(exp(1.0)) * 0.01)); }
__device__ __forceinline__ double d_beta()  { return exp(-0.004 / (log1p(exp(1.0)) * 0.02)); }

// Count "impossible-as-bf16" u16 patterns (f32 mantissa halves decode as huge/inf/nan).
__device__ __forceinline__ int sniff_part(const void* p, int nscan, int tid, int nthr) {
    const u16* q = (const u16*)p;
    int cnt = 0;
    for (int i = tid; i < nscan; i += nthr) {
        float v = bf2f(q[i]);
        if (!(fabsf(v) < 1e4f)) cnt++;
    }
    return cnt;
}
__device__ __forceinline__ int wave_sum(int c) {
#pragma unroll
    for (int d = 32; d >= 1; d >>= 1) c += __shfl_xor(c, d, 64);
    return c;
}

// 16 k-ascending FMAs into each of the 64 per-lane accumulators.
// W read wave-uniform from LDS (broadcast ds_read_b128, conflict-free).
// Chain order per output h: single accumulator, k ascending, fmaf — bit-exact
// match of the BLAS sgemm microkernel rounding (MUST NOT change).
__device__ __forceinline__ void acc_chunk(float* __restrict__ acc,
                                          const float* __restrict__ xr,
                                          const float* __restrict__ wbase) {
#pragma unroll
    for (int h = 0; h < 64; ++h) {
        const float4* wr = (const float4*)(wbase + h * NIN);
        const float4 w0 = wr[0], w1 = wr[1], w2 = wr[2], w3 = wr[3];
        float c = acc[h];
        c = fmaf(xr[0],  w0.x, c); c = fmaf(xr[1],  w0.y, c);
        c = fmaf(xr[2],  w0.z, c); c = fmaf(xr[3],  w0.w, c);
        c = fmaf(xr[4],  w1.x, c); c = fmaf(xr[5],  w1.y, c);
        c = fmaf(xr[6],  w1.z, c); c = fmaf(xr[7],  w1.w, c);
        c = fmaf(xr[8],  w2.x, c); c = fmaf(xr[9],  w2.y, c);
        c = fmaf(xr[10], w2.z, c); c = fmaf(xr[11], w2.w, c);
        c = fmaf(xr[12], w3.x, c); c = fmaf(xr[13], w3.y, c);
        c = fmaf(xr[14], w3.z, c); c = fmaf(xr[15], w3.w, c);
        acc[h] = c;
    }
}

// ---------------- Phase 1: cur[(t*B+b), h] = seq-fma dot(x[(t-1)*B+b,:], Wh[h,:]) in f32.
// One LANE per row, acc[64] in VGPRs; W broadcast from LDS; x via uint4 loads.
__global__ __launch_bounds__(256) void k_cur(const void* __restrict__ xv,
                                             const void* __restrict__ whv,
                                             float* __restrict__ cur) {
    const int NROWC = (T_STEPS - 1) * BATCH;  // 524160
    const int tid = threadIdx.x;
    __shared__ int s_cnt[2];
    __shared__ __align__(16) float whs[NH * NIN];  // [h][96] f32, rows 384B (16B-aligned)
    if (tid < 2) s_cnt[tid] = 0;
    __syncthreads();
    int c0 = sniff_part(xv, 512, tid, 256);
    int c1 = sniff_part(whv, 512, tid, 256);
    if (c0) atomicAdd(&s_cnt[0], c0);
    if (c1) atomicAdd(&s_cnt[1], c1);
    __syncthreads();
    const bool fx = s_cnt[0] >= 32, fw = s_cnt[1] >= 32;

    if (fw) {
        const float* w = (const float*)whv;
        for (int s = tid; s < NH * NIN; s += 256) whs[s] = w[s];
    } else {
        const u16* w = (const u16*)whv;
        for (int s = tid; s < NH * NIN; s += 256) whs[s] = bf2f(w[s]);
    }
    __syncthreads();

    const long r = (long)blockIdx.x * 256 + tid;  // one row per lane
    if (r >= NROWC) {
        // exactly 128 leftover threads in the last block: zero cur rows [0,128) (t=0)
        const long z = r - NROWC;
        if (z < BATCH) {
            float4 zero = {0.f, 0.f, 0.f, 0.f};
            float4* zp = (float4*)(cur + z * NH);
#pragma unroll
            for (int j = 0; j < 16; ++j) zp[j] = zero;
        }
        return;
    }

    float acc[64];
#pragma unroll
    for (int h = 0; h < 64; ++h) acc[h] = 0.f;

    if (!fx) {
        const uint4* xq = (const uint4*)((const u16*)xv + (size_t)r * NIN);  // 12 uint4/row
        uint4 n0 = xq[0], n1 = xq[1];  // prefetch chunk 0
#pragma unroll 1
        for (int kb = 0; kb < 6; ++kb) {
            const uint4 a = n0, b = n1;
            if (kb < 5) { n0 = xq[(kb + 1) * 2]; n1 = xq[(kb + 1) * 2 + 1]; }
            const unsigned ua[8] = {a.x, a.y, a.z, a.w, b.x, b.y, b.z, b.w};
            float xr[16];
#pragma unroll
            for (int j = 0; j < 8; ++j) {
                xr[2 * j]     = bf2f((u16)(ua[j] & 0xFFFFu));
                xr[2 * j + 1] = bf2f((u16)(ua[j] >> 16));
            }
            acc_chunk(acc, xr, whs + kb * 16);
        }
    } else {
        const float4* xq = (const float4*)((const float*)xv + (size_t)r * NIN);  // 24 float4/row
        float4 n0 = xq[0], n1 = xq[1], n2 = xq[2], n3 = xq[3];
#pragma unroll 1
        for (int kb = 0; kb < 6; ++kb) {
            const float4 a0 = n0, a1 = n1, a2 = n2, a3 = n3;
            if (kb < 5) {
                n0 = xq[(kb + 1) * 4];     n1 = xq[(kb + 1) * 4 + 1];
                n2 = xq[(kb + 1) * 4 + 2]; n3 = xq[(kb + 1) * 4 + 3];
            }
            const float xr[16] = {a0.x, a0.y, a0.z, a0.w, a1.x, a1.y, a1.z, a1.w,
                                  a2.x, a2.y, a2.z, a2.w, a3.x, a3.y, a3.z, a3.w};
            acc_chunk(acc, xr, whs + kb * 16);
        }
    }

    float4* op = (float4*)(cur + ((size_t)r + BATCH) * NH);
#pragma unroll
    for (int j = 0; j < 16; ++j) {
        float4 v;
        v.x = acc[4 * j]; v.y = acc[4 * j + 1]; v.z = acc[4 * j + 2]; v.w = acc[4 * j + 3];
        op[j] = v;
    }
}

// ---------------- Phase 2: sequential scan, f64 hidden states.
// 1 block = 1 batch element, 1 wave, lane = hidden neuron.
// Round-1 serial gather restored (round-2's always-8 batch regressed: avg
// spikes/step is low, fixed 8-read pipeline + tree + deep extraction chain
// cost more than it saved). Kept refinements:
//  - 2-wide read START: k0,k1 (k1 padded to zero row 64) issued together,
//    rec = (double)r0 + (double)r1 == ((0+r0)+r1) bit-exact; tail while
//    continues k-ascending for >=3 spikes. Saves one serialized LDS latency
//    on 2-spike steps, costs one pipelined read on 1-spike steps.
//  - decision hoist: s <=> fma(ombeta, rec, p) > q with p,q computed off the
//    gather path; carried syn/mem source expressions UNCHANGED.
//  - unclamped prefetch: tail loads over-read into the adjacent ftr region
//    (same d_ws allocation, values never consumed).
__global__ __launch_bounds__(64, 1) void k_scan(const float* __restrict__ cur,
                                                const void* __restrict__ vv,
                                                _Float16* __restrict__ ftr) {
    const int b = blockIdx.x, h = threadIdx.x;
    const double alpha = d_alpha(), beta = d_beta(), ombeta = 1.0 - beta;
    const float alphaf = (float)alpha, betaf = (float)beta, ombetaf = (float)ombeta;

    const bool fv = wave_sum(sniff_part(vv, 512, h, 64)) >= 32;

    __shared__ float vlds[65 * NH];  // vlds[k*64+h] = V[h][k]; row 64 = zeros (pad target)
    if (fv) {
        const float* vp = (const float*)vv;
        for (int s = h; s < NH * NH; s += 64) vlds[((s & 63) << 6) | (s >> 6)] = vp[s];
    } else {
        const u16* vp = (const u16*)vv;
        for (int s = h; s < NH * NH; s += 64) vlds[((s & 63) << 6) | (s >> 6)] = bf2f(vp[s]);
    }
    vlds[(64 << 6) | h] = 0.0f;  // zero pad row for the k1 slot
    __syncthreads();

    double syn = 0.0, mem = 0.0;
    float e = 0.f, f = 0.f, spkf = 0.f;
    unsigned long long mask = 0ull;

    const size_t STEP = (size_t)BATCH * NH;
    const float* cp = cur + (size_t)b * NH + h;
    _Float16* fp = ftr + (size_t)b * NH + h;

    float cbuf[8];  // 8-deep prefetch pipeline hides HBM latency on cur reads
#pragma unroll
    for (int j = 0; j < 8; ++j) cbuf[j] = cp[(size_t)j * STEP];

    for (int tt = 0; tt < T_STEPS; tt += 8) {
#pragma unroll
        for (int j = 0; j < 8; ++j) {
            const float c = cbuf[j];
            // unclamped: tail reads land in the ftr region (allocated, unused)
            cbuf[j] = cp[(size_t)(tt + j + 8) * STEP];

            // hoisted decision pieces (deps: prev-step syn/mem + c; computed
            // in the LDS-gather shadow)
            const double p = ombeta * fma(alpha, syn, (double)c);  // wb*(a*syn+c)
            const double q = 1.0 - beta * mem;

            double rec = 0.0;
            unsigned long long m = mask;
            if (m) {
                const int k0 = (int)__builtin_ctzll(m); m &= m - 1;
                const int k1 = m ? (int)__builtin_ctzll(m) : 64;
                const unsigned long long m2 = m ? (m & (m - 1)) : 0ull;
                const float r0 = vlds[(k0 << 6) | h];
                const float r1 = vlds[(k1 << 6) | h];
                rec = (double)r0 + (double)r1;  // == ((0+r0)+r1); pad r1==0 exact
                m = m2;
                while (m) {  // >=3 spikes: continue k-ascending (bit-exact order)
                    const int k = (int)__builtin_ctzll(m);
                    m &= m - 1;
                    rec += (double)vlds[(k << 6) | h];
                }
            }

            // spike decision: algebraically == (beta*mem' ... mem' > 1.0)
            const bool s = fma(ombeta, rec, p) > q;

            // carried states: SAME source expressions as the passing kernel
            syn = alpha * syn + ((double)c + rec);
            mem = beta * mem + ombeta * syn;

            // readout traces driven by PREVIOUS spikes (before this step's mask update)
            e = fmaf(alphaf, e, spkf);
            f = fmaf(betaf, f, ombetaf * e);
            fp[(size_t)(tt + j) * STEP] = (_Float16)f;

            mem = s ? 0.0 : mem;
            spkf = s ? 1.0f : 0.0f;
            mask = __ballot(s);
        }
    }
}

// ---------------- Phase 3: preds[t,b,o] = sum_h Wo[o,h]*f[t,b,h] -> f32 output [T,B,2].
// Stage 256 rows (32 KB f16) through LDS with coalesced dword loads; padded
// stride 34 dwords (bank stride 2 -> 2-way aliasing, free) for both write+read.
__global__ __launch_bounds__(256) void k_out(const _Float16* __restrict__ ftr,
                                             const void* __restrict__ wov,
                                             float* __restrict__ out) {
    const int tid = threadIdx.x;
    __shared__ unsigned tile[256 * 34];  // row r at tile[r*34 .. r*34+32)
    __shared__ float wo[2][64];
    const bool fo = sniff_part(wov, 120, 0, 1) >= 7;
    if (fo) {
        if (tid < 128) wo[tid >> 6][tid & 63] = ((const float*)wov)[tid];
    } else {
        if (tid < 128) wo[tid >> 6][tid & 63] = bf2f(((const u16*)wov)[tid]);
    }

    // coalesced stage: 256 rows * 32 dwords = 8192 dwords, 256 threads * 32 iters
    const unsigned* src = (const unsigned*)(ftr + (size_t)blockIdx.x * 256 * NH);
#pragma unroll
    for (int i = 0; i < 32; ++i) {
        const int s = i * 256 + tid;
        tile[(s >> 5) * 34 + (s & 31)] = src[s];
    }
    __syncthreads();

    const size_t idx = (size_t)blockIdx.x * 256 + tid;  // row = t*B + b
    const unsigned* up = &tile[tid * 34];
    float d0 = 0.f, d1 = 0.f;
#pragma unroll
    for (int j = 0; j < 32; ++j) {
        const unsigned u = up[j];
        const float f0 = (float)__builtin_bit_cast(_Float16, (unsigned short)(u & 0xFFFFu));
        const float f1 = (float)__builtin_bit_cast(_Float16, (unsigned short)(u >> 16));
        d0 = fmaf(f0, wo[0][2 * j], d0);
        d1 = fmaf(f0, wo[1][2 * j], d1);
        d0 = fmaf(f1, wo[0][2 * j + 1], d0);
        d1 = fmaf(f1, wo[1][2 * j + 1], d1);
    }
    float2 r; r.x = d0; r.y = d1;
    ((float2*)out)[idx] = r;  // f32 [T,B,2] row-major
}

// ---------------- Fallback: fully fused, zero workspace, f64 states, f32 output.
__global__ __launch_bounds__(64) void k_fused(const void* __restrict__ xv,
                                              const void* __restrict__ whv,
                                              const void* __restrict__ vv,
                                              const void* __restrict__ wov,
                                              float* __restrict__ out) {
    const int b = blockIdx.x, h = threadIdx.x;
    const double alpha = d_alpha(), beta = d_beta(), ombeta = 1.0 - beta;

    const bool fx = wave_sum(sniff_part(xv, 512, h, 64)) >= 32;
    const bool fw = wave_sum(sniff_part(whv, 512, h, 64)) >= 32;
    const bool fv = wave_sum(sniff_part(vv, 512, h, 64)) >= 32;
    const bool fo = wave_sum(sniff_part(wov, 120, h, 64)) >= 7;

    __shared__ float vlds[NH * NH];  // vlds[k*64+h] = V[h][k]
    __shared__ float whl[NIN * NH];  // whl[i*64+h] = Wh[h][i]
    if (fv) { const float* vp = (const float*)vv;
        for (int s = h; s < NH * NH; s += 64) vlds[((s & 63) << 6) | (s >> 6)] = vp[s]; }
    else    { const u16* vp = (const u16*)vv;
        for (int s = h; s < NH * NH; s += 64) vlds[((s & 63) << 6) | (s >> 6)] = bf2f(vp[s]); }
    if (fw) { const float* wp = (const float*)whv;
        for (int s = h; s < NH * NIN; s += 64) whl[(s % 96) * 64 + (s / 96)] = wp[s]; }
    else    { const u16* wp = (const u16*)whv;
        for (int s = h; s < NH * NIN; s += 64) whl[(s % 96) * 64 + (s / 96)] = bf2f(wp[s]); }
    __syncthreads();

    double wo0, wo1;
    if (fo) { wo0 = (double)((const float*)wov)[h]; wo1 = (double)((const float*)wov)[64 + h]; }
    else    { wo0 = (double)bf2f(((const u16*)wov)[h]); wo1 = (double)bf2f(((const u16*)wov)[64 + h]); }

    double syn = 0.0, mem = 0.0, syno0 = 0.0, memo0 = 0.0, syno1 = 0.0, memo1 = 0.0;
    double spkd = 0.0;
    unsigned long long mask = 0ull;

    for (int t = 0; t < T_STEPS; ++t) {
        float c = 0.0f;
        if (t > 0) {
            const size_t off = ((size_t)(t - 1) * BATCH + b) * NIN;
            if (fx) { const float* xp = (const float*)xv + off;
                for (int i = 0; i < NIN; ++i) c = fmaf(xp[i], whl[i * 64 + h], c); }
            else    { const u16* xp = (const u16*)xv + off;
                for (int i = 0; i < NIN; ++i) c = fmaf(bf2f(xp[i]), whl[i * 64 + h], c); }
        }
        double rec = 0.0;
        unsigned long long m = mask;
        while (m) { const int k = __builtin_ctzll(m); m &= m - 1; rec += (double)vlds[(k << 6) | h]; }

        syn = alpha * syn + ((double)c + rec);
        mem = beta * mem + ombeta * syn;

        double p0 = spkd * wo0, p1 = spkd * wo1;
#pragma unroll
        for (int d = 32; d >= 1; d >>= 1) { p0 += __shfl_xor(p0, d, 64); p1 += __shfl_xor(p1, d, 64); }
        syno0 = alpha * syno0 + p0;
        memo0 = beta * memo0 + ombeta * syno0;
        syno1 = alpha * syno1 + p1;
        memo1 = beta * memo1 + ombeta * syno1;
        if (h == 0) {
            const size_t w = ((size_t)t * BATCH + b) * 2;
            out[w] = (float)memo0;
            out[w + 1] = (float)memo1;
        }

        const bool s = mem > 1.0;
        mem = s ? 0.0 : mem;
        spkd = s ? 1.0 : 0.0;
        mask = __ballot(s);
    }
}

extern "C" void kernel_launch(void* const* d_in, const int* in_sizes, int n_in,
                              void* d_out, int out_size, void* d_ws, size_t ws_size,
                              hipStream_t stream) {
    (void)in_sizes; (void)out_size;
    if (n_in < 4) return;
    const void* x  = d_in[0];   // [T,B,IN]  f32 or bf16 (sniff-verified)
    const void* Wh = d_in[1];   // [H,IN]
    const void* V  = d_in[2];   // [H,H]
    const void* Wo = d_in[3];   // [OUT,H]
    float* out = (float*)d_out; // [T,B,2] float32

    const size_t NROW = (size_t)T_STEPS * BATCH;       // 524288
    const size_t curB = NROW * NH * sizeof(float);     // 134 MB
    const size_t ftrB = NROW * NH * sizeof(_Float16);  // 67 MB

    if (ws_size >= curB + ftrB) {
        float* cur = (float*)d_ws;
        _Float16* ftr = (_Float16*)((char*)d_ws + curB);
        // 2048 blocks * 256 threads = 524288 = 524160 compute rows + 128 zero-fill rows
        const int NBLK = (int)(NROW / 256);
        k_cur<<<NBLK, 256, 0, stream>>>(x, Wh, cur);
        k_scan<<<BATCH, 64, 0, stream>>>(cur, V, ftr);
        k_out<<<NROW / 256, 256, 0, stream>>>(ftr, Wo, out);
    } else {
        k_fused<<<BATCH, 64, 0, stream>>>(x, Wh, V, Wo, out);
    }
}

// Round 4
// 924.536 us; speedup vs baseline: 1.2758x; 1.0174x over previous
//
#include <hip/hip_runtime.h>
#include <cmath>

#define T_STEPS 4096
#define BATCH   128
#define NIN     96
#define NH      64

typedef unsigned short u16;

__device__ __forceinline__ float bf2f(u16 u) {
    unsigned v = ((unsigned)u) << 16;
    return __builtin_bit_cast(float, v);
}
// f64 decay constants, mirroring np.exp(-DT/TAU) f64 scalars (NEP-50 strong promotion)
__device__ __forceinline__ double d_alpha() { return exp(-0.004 / (log1p(exp(1.0)) * 0.01)); }
__device__ __forceinline__ double d_beta()  { return exp(-0.004 / (log1p(exp(1.0)) * 0.02)); }

// Count "impossible-as-bf16" u16 patterns (f32 mantissa halves decode as huge/inf/nan).
__device__ __forceinline__ int sniff_part(const void* p, int nscan, int tid, int nthr) {
    const u16* q = (const u16*)p;
    int cnt = 0;
    for (int i = tid; i < nscan; i += nthr) {
        float v = bf2f(q[i]);
        if (!(fabsf(v) < 1e4f)) cnt++;
    }
    return cnt;
}
__device__ __forceinline__ int wave_sum(int c) {
#pragma unroll
    for (int d = 32; d >= 1; d >>= 1) c += __shfl_xor(c, d, 64);
    return c;
}

// 16 k-ascending FMAs into each of the 64 per-lane accumulators.
// W read wave-uniform from LDS (broadcast ds_read_b128, conflict-free).
// Chain order per output h: single accumulator, k ascending, fmaf — bit-exact
// match of the BLAS sgemm microkernel rounding (MUST NOT change).
__device__ __forceinline__ void acc_chunk(float* __restrict__ acc,
                                          const float* __restrict__ xr,
                                          const float* __restrict__ wbase) {
#pragma unroll
    for (int h = 0; h < 64; ++h) {
        const float4* wr = (const float4*)(wbase + h * NIN);
        const float4 w0 = wr[0], w1 = wr[1], w2 = wr[2], w3 = wr[3];
        float c = acc[h];
        c = fmaf(xr[0],  w0.x, c); c = fmaf(xr[1],  w0.y, c);
        c = fmaf(xr[2],  w0.z, c); c = fmaf(xr[3],  w0.w, c);
        c = fmaf(xr[4],  w1.x, c); c = fmaf(xr[5],  w1.y, c);
        c = fmaf(xr[6],  w1.z, c); c = fmaf(xr[7],  w1.w, c);
        c = fmaf(xr[8],  w2.x, c); c = fmaf(xr[9],  w2.y, c);
        c = fmaf(xr[10], w2.z, c); c = fmaf(xr[11], w2.w, c);
        c = fmaf(xr[12], w3.x, c); c = fmaf(xr[13], w3.y, c);
        c = fmaf(xr[14], w3.z, c); c = fmaf(xr[15], w3.w, c);
        acc[h] = c;
    }
}

// ---------------- Phase 1: cur[(t*B+b), h] = seq-fma dot(x[(t-1)*B+b,:], Wh[h,:]) in f32.
// One LANE per row, acc[64] in VGPRs; W broadcast from LDS; x via uint4 loads.
__global__ __launch_bounds__(256) void k_cur(const void* __restrict__ xv,
                                             const void* __restrict__ whv,
                                             float* __restrict__ cur) {
    const int NROWC = (T_STEPS - 1) * BATCH;  // 524160
    const int tid = threadIdx.x;
    __shared__ int s_cnt[2];
    __shared__ __align__(16) float whs[NH * NIN];  // [h][96] f32, rows 384B (16B-aligned)
    if (tid < 2) s_cnt[tid] = 0;
    __syncthreads();
    int c0 = sniff_part(xv, 512, tid, 256);
    int c1 = sniff_part(whv, 512, tid, 256);
    if (c0) atomicAdd(&s_cnt[0], c0);
    if (c1) atomicAdd(&s_cnt[1], c1);
    __syncthreads();
    const bool fx = s_cnt[0] >= 32, fw = s_cnt[1] >= 32;

    if (fw) {
        const float* w = (const float*)whv;
        for (int s = tid; s < NH * NIN; s += 256) whs[s] = w[s];
    } else {
        const u16* w = (const u16*)whv;
        for (int s = tid; s < NH * NIN; s += 256) whs[s] = bf2f(w[s]);
    }
    __syncthreads();

    const long r = (long)blockIdx.x * 256 + tid;  // one row per lane
    if (r >= NROWC) {
        // exactly 128 leftover threads in the last block: zero cur rows [0,128) (t=0)
        const long z = r - NROWC;
        if (z < BATCH) {
            float4 zero = {0.f, 0.f, 0.f, 0.f};
            float4* zp = (float4*)(cur + z * NH);
#pragma unroll
            for (int j = 0; j < 16; ++j) zp[j] = zero;
        }
        return;
    }

    float acc[64];
#pragma unroll
    for (int h = 0; h < 64; ++h) acc[h] = 0.f;

    if (!fx) {
        const uint4* xq = (const uint4*)((const u16*)xv + (size_t)r * NIN);  // 12 uint4/row
        uint4 n0 = xq[0], n1 = xq[1];  // prefetch chunk 0
#pragma unroll 1
        for (int kb = 0; kb < 6; ++kb) {
            const uint4 a = n0, b = n1;
            if (kb < 5) { n0 = xq[(kb + 1) * 2]; n1 = xq[(kb + 1) * 2 + 1]; }
            const unsigned ua[8] = {a.x, a.y, a.z, a.w, b.x, b.y, b.z, b.w};
            float xr[16];
#pragma unroll
            for (int j = 0; j < 8; ++j) {
                xr[2 * j]     = bf2f((u16)(ua[j] & 0xFFFFu));
                xr[2 * j + 1] = bf2f((u16)(ua[j] >> 16));
            }
            acc_chunk(acc, xr, whs + kb * 16);
        }
    } else {
        const float4* xq = (const float4*)((const float*)xv + (size_t)r * NIN);  // 24 float4/row
        float4 n0 = xq[0], n1 = xq[1], n2 = xq[2], n3 = xq[3];
#pragma unroll 1
        for (int kb = 0; kb < 6; ++kb) {
            const float4 a0 = n0, a1 = n1, a2 = n2, a3 = n3;
            if (kb < 5) {
                n0 = xq[(kb + 1) * 4];     n1 = xq[(kb + 1) * 4 + 1];
                n2 = xq[(kb + 1) * 4 + 2]; n3 = xq[(kb + 1) * 4 + 3];
            }
            const float xr[16] = {a0.x, a0.y, a0.z, a0.w, a1.x, a1.y, a1.z, a1.w,
                                  a2.x, a2.y, a2.z, a2.w, a3.x, a3.y, a3.z, a3.w};
            acc_chunk(acc, xr, whs + kb * 16);
        }
    }

    float4* op = (float4*)(cur + ((size_t)r + BATCH) * NH);
#pragma unroll
    for (int j = 0; j < 16; ++j) {
        float4 v;
        v.x = acc[4 * j]; v.y = acc[4 * j + 1]; v.z = acc[4 * j + 2]; v.w = acc[4 * j + 3];
        op[j] = v;
    }
}

// ---------------- Phase 2: sequential scan, f64 hidden states.
// 1 block = 1 batch element, 1 wave, lane = hidden neuron.
// SOFTWARE-PIPELINED GATHER: step t's ballot immediately extracts k0/k1 and
// issues the two ds_reads for step t+1 (unconditional; pad row 64 = 0.0 keeps
// the f64 sum bit-exact). All of step t's state math (f64 syn/mem, e/f traces,
// f16 store, cbuf reload, p/q precompute) executes UNDER the LDS latency;
// r0/r1 are consumed at the top of the next iteration. sched_barrier(0) pins
// the read-issues before the f64 block. >=3-spike tail (mt) stays serial at
// the consume site (rare). Loop-carried chain: cmp -> extract/addr -> ds_read
// -> cvt/add -> fma -> cmp  (~155 cy/step vs ~341 before).
// Decision/state formulas identical to the passing round-3 kernel:
//   p = ombeta*fma(alpha,syn,c_next); q = 1 - beta*mem(post-reset);
//   s = fma(ombeta, rec, p) > q;  syn/mem carried expressions UNCHANGED.
__global__ __launch_bounds__(64, 1) void k_scan(const float* __restrict__ cur,
                                                const void* __restrict__ vv,
                                                _Float16* __restrict__ ftr) {
    const int b = blockIdx.x, h = threadIdx.x;
    const double alpha = d_alpha(), beta = d_beta(), ombeta = 1.0 - beta;
    const float alphaf = (float)alpha, betaf = (float)beta, ombetaf = (float)ombeta;

    const bool fv = wave_sum(sniff_part(vv, 512, h, 64)) >= 32;

    __shared__ float vlds[65 * NH];  // vlds[k*64+h] = V[h][k]; row 64 = zeros (pad target)
    if (fv) {
        const float* vp = (const float*)vv;
        for (int s = h; s < NH * NH; s += 64) vlds[((s & 63) << 6) | (s >> 6)] = vp[s];
    } else {
        const u16* vp = (const u16*)vv;
        for (int s = h; s < NH * NH; s += 64) vlds[((s & 63) << 6) | (s >> 6)] = bf2f(vp[s]);
    }
    vlds[(64 << 6) | h] = 0.0f;  // zero pad row for unused gather slots
    __syncthreads();

    double syn = 0.0, mem = 0.0;
    float e = 0.f, f = 0.f, spkf = 0.f;

    const size_t STEP = (size_t)BATCH * NH;
    const float* cp = cur + (size_t)b * NH + h;
    _Float16* fp = ftr + (size_t)b * NH + h;

    float cbuf[8];  // 8-deep prefetch pipeline hides HBM latency on cur reads
#pragma unroll
    for (int j = 0; j < 8; ++j) cbuf[j] = cp[(size_t)j * STEP];

    // pipeline state: pending gather reads for the CURRENT step
    float r0 = 0.f, r1 = 0.f;        // t=0: mask empty -> rec = 0+0
    unsigned long long mt = 0ull;    // residual mask (>=3 spikes), consume-side
    // p/q for t=0 (syn=mem=0, c_0=cbuf[0]); same formula as in-loop
    double p = ombeta * fma(alpha, syn, (double)cbuf[0]);
    double q = 1.0 - beta * mem;

    for (int tt = 0; tt < T_STEPS; tt += 8) {
#pragma unroll
        for (int j = 0; j < 8; ++j) {
            const int t = tt + j;
            const float c = cbuf[j];
            // unclamped prefetch reload: tail reads land in ftr region (allocated, unused)
            cbuf[j] = cp[(size_t)(t + 8) * STEP];

            // ---- consume pipelined gather for THIS step
            double rec = (double)r0 + (double)r1;  // == ((0+r0)+r1); pads exact
            while (mt) {  // >=3 spikes: continue k-ascending (bit-exact order)
                const int k = (int)__builtin_ctzll(mt);
                mt &= mt - 1;
                rec += (double)vlds[(k << 6) | h];
            }

            // ---- decision (algebraically == beta*mem + ombeta*syn' > 1)
            const bool s = fma(ombeta, rec, p) > q;
            const unsigned long long mask = __ballot(s);

            // ---- issue NEXT step's gather immediately (the critical path)
            {
                unsigned long long m = mask;
                const int k0 = m ? (int)__builtin_ctzll(m) : 64;
                m = m ? (m & (m - 1)) : 0ull;
                const int k1 = m ? (int)__builtin_ctzll(m) : 64;
                mt = m ? (m & (m - 1)) : 0ull;
                r0 = vlds[(k0 << 6) | h];
                r1 = vlds[(k1 << 6) | h];
            }
            __builtin_amdgcn_sched_barrier(0);  // pin read-issue before the f64 block

            // ---- off-critical-path: state updates under the LDS latency.
            // carried states: SAME source expressions as the passing kernel
            syn = alpha * syn + ((double)c + rec);
            mem = beta * mem + ombeta * syn;

            // readout traces driven by PREVIOUS spikes (old spkf), then store
            e = fmaf(alphaf, e, spkf);
            f = fmaf(betaf, f, ombetaf * e);
            fp[(size_t)t * STEP] = (_Float16)f;

            mem = s ? 0.0 : mem;
            spkf = s ? 1.0f : 0.0f;

            // p/q for step t+1 (c_{t+1}: j<7 -> old cbuf[j+1]; j==7 -> cbuf[0]
            // which was reloaded at j=0 of this tt-round to value t=tt+8)
            const float cn = cbuf[(j + 1) & 7];
            p = ombeta * fma(alpha, syn, (double)cn);
            q = 1.0 - beta * mem;
        }
    }
}

// ---------------- Phase 3: preds[t,b,o] = sum_h Wo[o,h]*f[t,b,h] -> f32 output [T,B,2].
// Stage 256 rows (32 KB f16) through LDS with coalesced dword loads; padded
// stride 34 dwords (bank stride 2 -> 2-way aliasing, free) for both write+read.
__global__ __launch_bounds__(256) void k_out(const _Float16* __restrict__ ftr,
                                             const void* __restrict__ wov,
                                             float* __restrict__ out) {
    const int tid = threadIdx.x;
    __shared__ unsigned tile[256 * 34];  // row r at tile[r*34 .. r*34+32)
    __shared__ float wo[2][64];
    const bool fo = sniff_part(wov, 120, 0, 1) >= 7;
    if (fo) {
        if (tid < 128) wo[tid >> 6][tid & 63] = ((const float*)wov)[tid];
    } else {
        if (tid < 128) wo[tid >> 6][tid & 63] = bf2f(((const u16*)wov)[tid]);
    }

    // coalesced stage: 256 rows * 32 dwords = 8192 dwords, 256 threads * 32 iters
    const unsigned* src = (const unsigned*)(ftr + (size_t)blockIdx.x * 256 * NH);
#pragma unroll
    for (int i = 0; i < 32; ++i) {
        const int s = i * 256 + tid;
        tile[(s >> 5) * 34 + (s & 31)] = src[s];
    }
    __syncthreads();

    const size_t idx = (size_t)blockIdx.x * 256 + tid;  // row = t*B + b
    const unsigned* up = &tile[tid * 34];
    float d0 = 0.f, d1 = 0.f;
#pragma unroll
    for (int j = 0; j < 32; ++j) {
        const unsigned u = up[j];
        const float f0 = (float)__builtin_bit_cast(_Float16, (unsigned short)(u & 0xFFFFu));
        const float f1 = (float)__builtin_bit_cast(_Float16, (unsigned short)(u >> 16));
        d0 = fmaf(f0, wo[0][2 * j], d0);
        d1 = fmaf(f0, wo[1][2 * j], d1);
        d0 = fmaf(f1, wo[0][2 * j + 1], d0);
        d1 = fmaf(f1, wo[1][2 * j + 1], d1);
    }
    float2 r; r.x = d0; r.y = d1;
    ((float2*)out)[idx] = r;  // f32 [T,B,2] row-major
}

// ---------------- Fallback: fully fused, zero workspace, f64 states, f32 output.
__global__ __launch_bounds__(64) void k_fused(const void* __restrict__ xv,
                                              const void* __restrict__ whv,
                                              const void* __restrict__ vv,
                                              const void* __restrict__ wov,
                                              float* __restrict__ out) {
    const int b = blockIdx.x, h = threadIdx.x;
    const double alpha = d_alpha(), beta = d_beta(), ombeta = 1.0 - beta;

    const bool fx = wave_sum(sniff_part(xv, 512, h, 64)) >= 32;
    const bool fw = wave_sum(sniff_part(whv, 512, h, 64)) >= 32;
    const bool fv = wave_sum(sniff_part(vv, 512, h, 64)) >= 32;
    const bool fo = wave_sum(sniff_part(wov, 120, h, 64)) >= 7;

    __shared__ float vlds[NH * NH];  // vlds[k*64+h] = V[h][k]
    __shared__ float whl[NIN * NH];  // whl[i*64+h] = Wh[h][i]
    if (fv) { const float* vp = (const float*)vv;
        for (int s = h; s < NH * NH; s += 64) vlds[((s & 63) << 6) | (s >> 6)] = vp[s]; }
    else    { const u16* vp = (const u16*)vv;
        for (int s = h; s < NH * NH; s += 64) vlds[((s & 63) << 6) | (s >> 6)] = bf2f(vp[s]); }
    if (fw) { const float* wp = (const float*)whv;
        for (int s = h; s < NH * NIN; s += 64) whl[(s % 96) * 64 + (s / 96)] = wp[s]; }
    else    { const u16* wp = (const u16*)whv;
        for (int s = h; s < NH * NIN; s += 64) whl[(s % 96) * 64 + (s / 96)] = bf2f(wp[s]); }
    __syncthreads();

    double wo0, wo1;
    if (fo) { wo0 = (double)((const float*)wov)[h]; wo1 = (double)((const float*)wov)[64 + h]; }
    else    { wo0 = (double)bf2f(((const u16*)wov)[h]); wo1 = (double)bf2f(((const u16*)wov)[64 + h]); }

    double syn = 0.0, mem = 0.0, syno0 = 0.0, memo0 = 0.0, syno1 = 0.0, memo1 = 0.0;
    double spkd = 0.0;
    unsigned long long mask = 0ull;

    for (int t = 0; t < T_STEPS; ++t) {
        float c = 0.0f;
        if (t > 0) {
            const size_t off = ((size_t)(t - 1) * BATCH + b) * NIN;
            if (fx) { const float* xp = (const float*)xv + off;
                for (int i = 0; i < NIN; ++i) c = fmaf(xp[i], whl[i * 64 + h], c); }
            else    { const u16* xp = (const u16*)xv + off;
                for (int i = 0; i < NIN; ++i) c = fmaf(bf2f(xp[i]), whl[i * 64 + h], c); }
        }
        double rec = 0.0;
        unsigned long long m = mask;
        while (m) { const int k = __builtin_ctzll(m); m &= m - 1; rec += (double)vlds[(k << 6) | h]; }

        syn = alpha * syn + ((double)c + rec);
        mem = beta * mem + ombeta * syn;

        double p0 = spkd * wo0, p1 = spkd * wo1;
#pragma unroll
        for (int d = 32; d >= 1; d >>= 1) { p0 += __shfl_xor(p0, d, 64); p1 += __shfl_xor(p1, d, 64); }
        syno0 = alpha * syno0 + p0;
        memo0 = beta * memo0 + ombeta * syno0;
        syno1 = alpha * syno1 + p1;
        memo1 = beta * memo1 + ombeta * syno1;
        if (h == 0) {
            const size_t w = ((size_t)t * BATCH + b) * 2;
            out[w] = (float)memo0;
            out[w + 1] = (float)memo1;
        }

        const bool s = mem > 1.0;
        mem = s ? 0.0 : mem;
        spkd = s ? 1.0 : 0.0;
        mask = __ballot(s);
    }
}

extern "C" void kernel_launch(void* const* d_in, const int* in_sizes, int n_in,
                              void* d_out, int out_size, void* d_ws, size_t ws_size,
                              hipStream_t stream) {
    (void)in_sizes; (void)out_size;
    if (n_in < 4) return;
    const void* x  = d_in[0];   // [T,B,IN]  f32 or bf16 (sniff-verified)
    const void* Wh = d_in[1];   // [H,IN]
    const void* V  = d_in[2];   // [H,H]
    const void* Wo = d_in[3];   // [OUT,H]
    float* out = (float*)d_out; // [T,B,2] float32

    const size_t NROW = (size_t)T_STEPS * BATCH;       // 524288
    const size_t curB = NROW * NH * sizeof(float);     // 134 MB
    const size_t ftrB = NROW * NH * sizeof(_Float16);  // 67 MB

    if (ws_size >= curB + ftrB) {
        float* cur = (float*)d_ws;
        _Float16* ftr = (_Float16*)((char*)d_ws + curB);
        // 2048 blocks * 256 threads = 524288 = 524160 compute rows + 128 zero-fill rows
        const int NBLK = (int)(NROW / 256);
        k_cur<<<NBLK, 256, 0, stream>>>(x, Wh, cur);
        k_scan<<<BATCH, 64, 0, stream>>>(cur, V, ftr);
        k_out<<<NROW / 256, 256, 0, stream>>>(ftr, Wo, out);
    } else {
        k_fused<<<BATCH, 64, 0, stream>>>(x, Wh, V, Wo, out);
    }
}